// Round 8
// baseline (109.188 us; speedup 1.0000x reference)
//
#include <hip/hip_runtime.h>

typedef unsigned long long u64;

#define HH 1024
#define WW 2048
#define NN (HH*WW)
#define GRID 512
#define BLOCK 256
#define PXT 16
#define CHUNK (PXT*BLOCK)       // 4096 pixels per block

// Flat one-hop exchange: each block writes 2 tagged u64 slots per barrier
// (double-buffered by token parity); every block gathers all 512x2 slots and
// reduces redundantly. Relaxed 64-bit atomics are self-validating via the tag
// byte -> no fences anywhere.
// slotA: tag(8)<<56 | f32bits(bv)<<24 | bi (21 bits, NN = 2^21)
// slotB: tag(8)<<56 | lps(13)<<26 | lin(13)<<13 | lu(13)   (counts <= 4096)
struct Coord { u64 arr[2][GRID][2]; };

// XLA expands logistic(x) as 0.5 + 0.5*tanh(0.5*x) — match that boundary.
__device__ __forceinline__ float sigmoid_ref(float x) {
  #pragma clang fp contract(off)
  return 0.5f + 0.5f * tanhf(0.5f * x);
}

__device__ __forceinline__ void slot_store(u64* p, u64 v) {
  __hip_atomic_store(p, v, __ATOMIC_RELAXED, __HIP_MEMORY_SCOPE_AGENT);
}
__device__ __forceinline__ u64 slot_load(u64* p) {
  return __hip_atomic_load(p, __ATOMIC_RELAXED, __HIP_MEMORY_SCOPE_AGENT);
}

__device__ void barrier_exchange(Coord* __restrict__ c, const float* __restrict__ pred,
                                 int b, int t, int tok,
                                 float bv, int bi, int lu, int lps, int lin,
                                 float& sval, int& sidx, int& uncl, int& psum, int& inter,
                                 float& cx, float& cy, float& s0, float& s1)
{
  #pragma clang fp contract(off)
  __shared__ float wv[2][4], gv[2][4];
  __shared__ int   wi[2][4], wu[2][4], wp[2][4], wn[2][4];
  __shared__ int   gi[2][4], gu[2][4], gp[2][4], gn[2][4];
  const int par = tok & 1;
  const int w = t >> 6, lane = t & 63;
  const unsigned tg = (unsigned)tok & 0xFFu;

  // ---- reduce own block (xor-butterfly: all lanes get the wave result) ----
  for (int off = 32; off; off >>= 1) {
    float v  = __shfl_xor(bv, off);
    int   ix = __shfl_xor(bi, off);
    int   a  = __shfl_xor(lu, off);
    int   p2 = __shfl_xor(lps, off);
    int   q2 = __shfl_xor(lin, off);
    if (v > bv || (v == bv && ix < bi)) { bv = v; bi = ix; }
    lu += a; lps += p2; lin += q2;
  }
  if (lane == 0) { wv[par][w]=bv; wi[par][w]=bi; wu[par][w]=lu; wp[par][w]=lps; wn[par][w]=lin; }
  __syncthreads();
  float v0 = wv[par][0]; int i0 = wi[par][0];
  int u0 = wu[par][0], p0 = wp[par][0], n0 = wn[par][0];
  #pragma unroll
  for (int j = 1; j < 4; ++j) {
    float vj = wv[par][j]; int ij = wi[par][j];
    if (vj > v0 || (vj == v0 && ij < i0)) { v0 = vj; i0 = ij; }
    u0 += wu[par][j]; p0 += wp[par][j]; n0 += wn[par][j];
  }
  if (t == 0) {
    slot_store(&c->arr[par][b][0],
               ((u64)tg << 56) | ((u64)__float_as_uint(v0) << 24) | (u64)(unsigned)i0);
    slot_store(&c->arr[par][b][1],
               ((u64)tg << 56) | ((u64)(unsigned)p0 << 26) |
               ((u64)(unsigned)n0 << 13) | (u64)(unsigned)u0);
  }

  // ---- gather: thread t owns blocks t and t+BLOCK (4 loads issued together) ----
  u64* pA = &c->arr[par][t][0];
  u64* pB = &c->arr[par][t + BLOCK][0];
  u64 a0, a1, b0, b1;
  for (;;) {
    a0 = slot_load(pA);     a1 = slot_load(pA + 1);
    b0 = slot_load(pB);     b1 = slot_load(pB + 1);
    if ((unsigned)(a0 >> 56) == tg && (unsigned)(a1 >> 56) == tg &&
        (unsigned)(b0 >> 56) == tg && (unsigned)(b1 >> 56) == tg) break;
    __builtin_amdgcn_s_sleep(1);
  }
  float v1 = __uint_as_float((unsigned)(a0 >> 24));
  int   i1 = (int)(a0 & 0xFFFFFFull);
  float v2 = __uint_as_float((unsigned)(b0 >> 24));
  int   i2 = (int)(b0 & 0xFFFFFFull);
  if (v2 > v1 || (v2 == v1 && i2 < i1)) { v1 = v2; i1 = i2; }
  int lps2 = (int)((a1 >> 26) & 0x1FFFu) + (int)((b1 >> 26) & 0x1FFFu);
  int lin2 = (int)((a1 >> 13) & 0x1FFFu) + (int)((b1 >> 13) & 0x1FFFu);
  int lu2  = (int)(a1 & 0x1FFFu)         + (int)(b1 & 0x1FFFu);

  for (int off = 32; off; off >>= 1) {
    float v  = __shfl_xor(v1, off);
    int   ix = __shfl_xor(i1, off);
    int   a  = __shfl_xor(lu2, off);
    int   p2 = __shfl_xor(lps2, off);
    int   q2 = __shfl_xor(lin2, off);
    if (v > v1 || (v == v1 && ix < i1)) { v1 = v; i1 = ix; }
    lu2 += a; lps2 += p2; lin2 += q2;
  }
  if (lane == 0) { gv[par][w]=v1; gi[par][w]=i1; gu[par][w]=lu2; gp[par][w]=lps2; gn[par][w]=lin2; }
  __syncthreads();
  float fv = gv[par][0]; int fi = gi[par][0];
  int fu = gu[par][0], fp = gp[par][0], fn = gn[par][0];
  #pragma unroll
  for (int j = 1; j < 4; ++j) {
    float vj = gv[par][j]; int ij = gi[par][j];
    if (vj > fv || (vj == fv && ij < fi)) { fv = vj; fi = ij; }
    fu += gu[par][j]; fp += gp[par][j]; fn += gn[par][j];
  }
  sval = fv; sidx = fi; uncl = fu; psum = fp; inter = fn;
  // center + sigma: every thread recomputes identically (same pred values,
  // same op order -> grid-consistent, and identical math to the reference)
  cx = tanhf(pred[fi])      + (2.0f / 2047.0f) * (float)(fi & (WW - 1));
  cy = tanhf(pred[NN + fi]) + (1.0f / 1023.0f) * (float)(fi >> 11);
  s0 = expf(pred[2 * NN + fi] * 10.0f);
  s1 = expf(pred[3 * NN + fi] * 10.0f);
}

__global__ void init_kernel(Coord* c) {
  int t = blockIdx.x * blockDim.x + threadIdx.x;
  u64* p = (u64*)c;
  int n = (int)(sizeof(Coord) / 8);
  if (t < n) p[t] = 0;
}

__global__ __launch_bounds__(BLOCK, 2)
void cluster_kernel(const float* __restrict__ pred,
                    int* __restrict__ out,
                    Coord* __restrict__ c)
{
  #pragma clang fp contract(off)
  const int b = blockIdx.x, t = threadIdx.x;
  const int base = b * CHUNK;

  const float xstep = 2.0f / 2047.0f;   // jnp.linspace(0,2,2048) step, f32
  const float ystep = 1.0f / 1023.0f;   // jnp.linspace(0,1,1024) step, f32

  // ---- stage 1: load once, keep everything in registers ----
  float ex[PXT], ey[PXT], sd[PXT];
  unsigned mbits = 0, ubits;
  float bv = -1.0f; int bi = 0; int mc = 0;
  #pragma unroll
  for (int k = 0; k < PXT; ++k) {
    int i = base + t + k * BLOCK;
    float seed = sigmoid_ref(pred[6 * NN + i]);
    sd[k] = seed;
    unsigned m = (seed > 0.5f) ? 1u : 0u;
    mbits |= m << k;
    ex[k] = tanhf(pred[i])      + xstep * (float)(i & (WW - 1));
    ey[k] = tanhf(pred[NN + i]) + ystep * (float)(i >> 11);
    out[i] = 0;
    mc += (int)m;
    float scv = m ? seed : 0.0f;
    if (scv > bv) { bv = scv; bi = i; }  // i increasing -> first max kept
  }
  ubits = mbits;

  float sval, cx, cy, s0, s1; int sidx, un, psum, inter;
  int tok = 1;
  barrier_exchange(c, pred, b, t, tok, bv, bi, mc, 0, 0,
                   sval, sidx, un, psum, inter, cx, cy, s0, s1); tok++;

  // ---- main loop: one flat fence-free barrier per iteration ----
  int count = 1;
  unsigned prev_pr = 0;
  for (int it = 0; it < 8192; ++it) {
    // deferred label write for the previous segment (before break checks!)
    if (it) {
      bool accept = (psum > 160) &&
                    ((float)inter / (float)(psum > 1 ? psum : 1) > 0.5f);
      if (accept) {
        #pragma unroll
        for (int k = 0; k < PXT; ++k)
          if ((prev_pr >> k) & 1u) out[base + t + k * BLOCK] = count;
        count++;
      }
    }
    if (un <= 160) break;          // cond: uncl.sum() > min_pixel
    if (!(sval >= 0.5f)) break;    // go == false -> stop, no state change

    // seed-pixel bit within this thread's pixels (i = base + t + k*BLOCK)
    int rel = sidx - base;
    unsigned sbit = 0;
    if (rel >= 0 && rel < CHUNK && (rel & (BLOCK - 1)) == t)
      sbit = 1u << (rel >> 8);

    // proposal bits (decision-path math identical to reference)
    unsigned pr = 0;
    #pragma unroll
    for (int k = 0; k < PXT; ++k) {
      float dx = ex[k] - cx, dy = ey[k] - cy;
      float dsq = (dx * dx) * s0 + (dy * dy) * s1;
      float dist = expf(-dsq);
      pr |= ((dist > 0.5f) ? 1u : 0u) << k;
    }
    pr &= mbits;
    int lps = __popc(pr);
    int lin = __popc(pr & ubits & ~sbit);  // uncl2 & proposal
    ubits &= ~pr; ubits &= ~sbit;          // uncl_new
    int lu = __popc(ubits);

    // next-seed argmax over remaining unclustered (static indices only)
    bv = -1.0f; bi = 0;
    #pragma unroll
    for (int k = 0; k < PXT; ++k) {
      if (((ubits >> k) & 1u) && sd[k] > bv) { bv = sd[k]; bi = base + t + k * BLOCK; }
    }
    prev_pr = pr;
    barrier_exchange(c, pred, b, t, tok, bv, bi, lu, lps, lin,
                     sval, sidx, un, psum, inter, cx, cy, s0, s1); tok++;
  }
}

extern "C" void kernel_launch(void* const* d_in, const int* in_sizes, int n_in,
                              void* d_out, int out_size, void* d_ws, size_t ws_size,
                              hipStream_t stream) {
  const float* pred = (const float*)d_in[0];
  int* out = (int*)d_out;
  Coord* c = (Coord*)d_ws;

  init_kernel<<<dim3((sizeof(Coord)/8 + 255)/256), dim3(256), 0, stream>>>(c);

  // Normal launch: co-residency of 512 blocks at 2 blocks/CU is guaranteed by
  // __launch_bounds__(256,2) (VGPR<=256, small LDS) on 256 CUs.
  cluster_kernel<<<dim3(GRID), dim3(BLOCK), 0, stream>>>(pred, out, c);
}

// Round 9
// 100.931 us; speedup vs baseline: 1.0818x; 1.0818x over previous
//
#include <hip/hip_runtime.h>

typedef unsigned long long u64;

#define HH 1024
#define WW 2048
#define NN (HH*WW)
#define GRID 512
#define BLOCK 256
#define PXT 16
#define CHUNK (PXT*BLOCK)       // 4096 pixels per block

// One-hop flat exchange, fence-free. Per barrier each block stores 2 tagged
// u64 slots (double-buffered by token parity). Wave0 of every block gathers
// all A-slots (argmax), wave1 gathers all B-slots (sums); per-lane done-masks
// avoid re-loading valid slots.
//  A-slot: [tag:12][f32bits(bv):30][NN-1-idx:21]  (u64 max == argmax, min-idx tiebreak)
//  B-slot: [tag:12][zero:13][lps:13][lin:13][lu:13]
struct Coord { u64 A[2][GRID]; u64 B[2][GRID]; };

// XLA expands logistic(x) as 0.5 + 0.5*tanh(0.5*x) — match that boundary.
__device__ __forceinline__ float sigmoid_ref(float x) {
  #pragma clang fp contract(off)
  return 0.5f + 0.5f * tanhf(0.5f * x);
}

__device__ __forceinline__ void slot_store(u64* p, u64 v) {
  __hip_atomic_store(p, v, __ATOMIC_RELAXED, __HIP_MEMORY_SCOPE_AGENT);
}
__device__ __forceinline__ u64 slot_load(u64* p) {
  return __hip_atomic_load(p, __ATOMIC_RELAXED, __HIP_MEMORY_SCOPE_AGENT);
}

__device__ void barrier_exchange(Coord* __restrict__ c, const float* __restrict__ pred,
                                 int b, int t, int tok,
                                 float bv, int bi, int lu, int lps, int lin,
                                 float& sval, int& sidx, int& uncl, int& psum, int& inter,
                                 float& cx, float& cy, float& s0, float& s1)
{
  #pragma clang fp contract(off)
  __shared__ u64 wA[2][4], wS[2][4];
  __shared__ u64 shA[2], shB[2];
  __shared__ int shLU[2];
  const int par = tok & 1, w = t >> 6, lane = t & 63;
  const unsigned tg = (unsigned)tok & 0xFFFu;

  // ---- block-local reduce: 2 packed butterflies ----
  unsigned fb = 0; int ic = 0;
  if (bv >= 0.0f) { fb = __float_as_uint(bv); ic = bi; }   // empty -> (0.0, idx 0)
  u64 am = ((u64)fb << 21) | (u64)(unsigned)(NN - 1 - ic);
  u64 sm = ((u64)(unsigned)lps << 42) | ((u64)(unsigned)lin << 21) | (u64)(unsigned)lu;
  for (int off = 32; off; off >>= 1) {
    u64 o = __shfl_xor(am, off);
    if (o > am) am = o;
    sm += __shfl_xor(sm, off);
  }
  if (lane == 0) { wA[par][w] = am; wS[par][w] = sm; }
  __syncthreads();

  if (w == 0) {
    // combine 4 waves + store both slots (lane 0)
    u64 A0 = wA[par][0], S0 = wS[par][0];
    #pragma unroll
    for (int j = 1; j < 4; ++j) {
      if (wA[par][j] > A0) A0 = wA[par][j];
      S0 += wS[par][j];
    }
    if (lane == 0) {
      u64 bp = ((u64)tg << 52) | ((S0 >> 42) << 26) |
               (((S0 >> 21) & 0x1FFFu) << 13) | (S0 & 0x1FFFu);
      slot_store(&c->A[par][b], ((u64)tg << 52) | A0);
      slot_store(&c->B[par][b], bp);
    }
    // gather all A-slots: lane owns 8, poll only not-yet-valid ones
    u64 q0=0,q1=0,q2=0,q3=0,q4=0,q5=0,q6=0,q7=0;
    unsigned done = 0;
    u64* basep = &c->A[par][lane * 8];
    while (done != 0xFFu) {
      #define POLL(J, QV) if (!((done >> J) & 1u)) { \
        u64 v = slot_load(basep + J); \
        if ((unsigned)(v >> 52) == tg) { QV = v; done |= 1u << J; } }
      POLL(0,q0) POLL(1,q1) POLL(2,q2) POLL(3,q3)
      POLL(4,q4) POLL(5,q5) POLL(6,q6) POLL(7,q7)
      #undef POLL
      if (done != 0xFFu) __builtin_amdgcn_s_sleep(1);
    }
    u64 m = q0;
    if (q1 > m) m = q1; if (q2 > m) m = q2; if (q3 > m) m = q3;
    if (q4 > m) m = q4; if (q5 > m) m = q5; if (q6 > m) m = q6; if (q7 > m) m = q7;
    for (int off = 32; off; off >>= 1) { u64 o = __shfl_xor(m, off); if (o > m) m = o; }
    if (lane == 0) shA[par] = m & ~(0xFFFull << 52);   // strip tag
  } else if (w == 1) {
    // gather all B-slots
    u64 q0=0,q1=0,q2=0,q3=0,q4=0,q5=0,q6=0,q7=0;
    unsigned done = 0;
    u64* basep = &c->B[par][lane * 8];
    while (done != 0xFFu) {
      #define POLL(J, QV) if (!((done >> J) & 1u)) { \
        u64 v = slot_load(basep + J); \
        if ((unsigned)(v >> 52) == tg) { QV = v; done |= 1u << J; } }
      POLL(0,q0) POLL(1,q1) POLL(2,q2) POLL(3,q3)
      POLL(4,q4) POLL(5,q5) POLL(6,q6) POLL(7,q7)
      #undef POLL
      if (done != 0xFFu) __builtin_amdgcn_s_sleep(1);
    }
    int lp = 0, ln = 0, lq = 0;
    #define ACC(QV) lp += (int)((QV >> 26) & 0x1FFFu); \
                    ln += (int)((QV >> 13) & 0x1FFFu); \
                    lq += (int)(QV & 0x1FFFu);
    ACC(q0) ACC(q1) ACC(q2) ACC(q3) ACC(q4) ACC(q5) ACC(q6) ACC(q7)
    #undef ACC
    u64 pk = ((u64)(unsigned)lp << 32) | (u64)(unsigned)ln;
    for (int off = 32; off; off >>= 1) { pk += __shfl_xor(pk, off); lq += __shfl_xor(lq, off); }
    if (lane == 0) { shB[par] = pk; shLU[par] = lq; }
  }
  __syncthreads();

  u64 m = shA[par];
  sval = __uint_as_float((unsigned)((m >> 21) & 0x3FFFFFFFu));
  int fi = NN - 1 - (int)(m & 0x1FFFFFu);
  sidx = fi;
  u64 pk = shB[par];
  psum = (int)(pk >> 32); inter = (int)(pk & 0xFFFFFFFFu); uncl = shLU[par];
  // center + sigma: every thread recomputes identically (read-only pred,
  // same op order -> grid-consistent, identical math to the reference)
  cx = tanhf(pred[fi])      + (2.0f / 2047.0f) * (float)(fi & (WW - 1));
  cy = tanhf(pred[NN + fi]) + (1.0f / 1023.0f) * (float)(fi >> 11);
  s0 = expf(pred[2 * NN + fi] * 10.0f);
  s1 = expf(pred[3 * NN + fi] * 10.0f);
}

__global__ void init_kernel(Coord* c) {
  int t = blockIdx.x * blockDim.x + threadIdx.x;
  u64* p = (u64*)c;
  int n = (int)(sizeof(Coord) / 8);
  if (t < n) p[t] = 0;
}

__global__ __launch_bounds__(BLOCK, 2)
void cluster_kernel(const float* __restrict__ pred,
                    int* __restrict__ out,
                    Coord* __restrict__ c)
{
  #pragma clang fp contract(off)
  const int b = blockIdx.x, t = threadIdx.x;
  const int base = b * CHUNK;

  const float xstep = 2.0f / 2047.0f;   // jnp.linspace(0,2,2048) step, f32
  const float ystep = 1.0f / 1023.0f;   // jnp.linspace(0,1,1024) step, f32

  // ---- stage 1: load once, keep everything in registers ----
  float ex[PXT], ey[PXT], sd[PXT];
  unsigned mbits = 0, ubits;
  float bv = -1.0f; int bi = 0; int mc = 0;
  #pragma unroll
  for (int k = 0; k < PXT; ++k) {
    int i = base + t + k * BLOCK;
    float seed = sigmoid_ref(pred[6 * NN + i]);
    sd[k] = seed;
    unsigned m = (seed > 0.5f) ? 1u : 0u;
    mbits |= m << k;
    ex[k] = tanhf(pred[i])      + xstep * (float)(i & (WW - 1));
    ey[k] = tanhf(pred[NN + i]) + ystep * (float)(i >> 11);
    out[i] = 0;
    mc += (int)m;
    float scv = m ? seed : 0.0f;
    if (scv > bv) { bv = scv; bi = i; }  // i increasing -> first max kept
  }
  ubits = mbits;

  float sval, cx, cy, s0, s1; int sidx, un, psum, inter;
  int tok = 1;
  barrier_exchange(c, pred, b, t, tok, bv, bi, mc, 0, 0,
                   sval, sidx, un, psum, inter, cx, cy, s0, s1); tok++;

  // ---- main loop: one flat fence-free barrier per iteration ----
  int count = 1;
  unsigned prev_pr = 0;
  for (int it = 0; it < 4000; ++it) {   // cap < 4096 so tag never aliases init 0
    // deferred label write for the previous segment (before break checks!)
    if (it) {
      bool accept = (psum > 160) &&
                    ((float)inter / (float)(psum > 1 ? psum : 1) > 0.5f);
      if (accept) {
        #pragma unroll
        for (int k = 0; k < PXT; ++k)
          if ((prev_pr >> k) & 1u) out[base + t + k * BLOCK] = count;
        count++;
      }
    }
    if (un <= 160) break;          // cond: uncl.sum() > min_pixel
    if (!(sval >= 0.5f)) break;    // go == false -> stop, no state change

    // seed-pixel bit within this thread's pixels (i = base + t + k*BLOCK)
    int rel = sidx - base;
    unsigned sbit = 0;
    if (rel >= 0 && rel < CHUNK && (rel & (BLOCK - 1)) == t)
      sbit = 1u << (rel >> 8);

    // proposal bits (decision-path math identical to reference)
    unsigned pr = 0;
    #pragma unroll
    for (int k = 0; k < PXT; ++k) {
      float dx = ex[k] - cx, dy = ey[k] - cy;
      float dsq = (dx * dx) * s0 + (dy * dy) * s1;
      float dist = expf(-dsq);
      pr |= ((dist > 0.5f) ? 1u : 0u) << k;
    }
    pr &= mbits;
    int lps = __popc(pr);
    int lin = __popc(pr & ubits & ~sbit);  // uncl2 & proposal
    ubits &= ~pr; ubits &= ~sbit;          // uncl_new
    int lu = __popc(ubits);

    // next-seed argmax over remaining unclustered (static indices only)
    bv = -1.0f; bi = 0;
    #pragma unroll
    for (int k = 0; k < PXT; ++k) {
      if (((ubits >> k) & 1u) && sd[k] > bv) { bv = sd[k]; bi = base + t + k * BLOCK; }
    }
    prev_pr = pr;
    barrier_exchange(c, pred, b, t, tok, bv, bi, lu, lps, lin,
                     sval, sidx, un, psum, inter, cx, cy, s0, s1); tok++;
  }
}

extern "C" void kernel_launch(void* const* d_in, const int* in_sizes, int n_in,
                              void* d_out, int out_size, void* d_ws, size_t ws_size,
                              hipStream_t stream) {
  const float* pred = (const float*)d_in[0];
  int* out = (int*)d_out;
  Coord* c = (Coord*)d_ws;

  init_kernel<<<dim3((unsigned)((sizeof(Coord)/8 + 255)/256)), dim3(256), 0, stream>>>(c);

  // Normal launch: co-residency of 512 blocks at 2 blocks/CU is guaranteed by
  // __launch_bounds__(256,2) (VGPR<=256, small LDS) on 256 CUs.
  cluster_kernel<<<dim3(GRID), dim3(BLOCK), 0, stream>>>(pred, out, c);
}